// Round 11
// baseline (798.450 us; speedup 1.0000x reference)
//
#include <hip/hip_runtime.h>

#pragma clang fp contract(off)

#define TOLD 60000
#define TNEW 60000
#define NVERT 30000
#define MAXSTEPS 300
#define THSZ 131072                  // tet-key hash slots (exact, CAS)
#define FHSZ 131072                  // exact CAS face table (DM-collision fallback only)
#define EMPTY64 0xFFFFFFFFFFFFFFFFULL
#define NWGR 60                      // prio vertex ranges (500 verts each)
#define VRANGE 500
#define NSLICE 16                    // prio tet slices
#define TSLICE (TOLD / NSLICE)       // 3750

// K1 block-range split
#define NB_SETUP 235                 // ceil(60000/256)
#define NB_PRIO  (NWGR * NSLICE)     // 960
#define NB_NEWG  235
// K2 block-range split
#define NB_FACE  938                 // ceil(240000/256)
#define NB_FOLD  118                 // ceil(30000/256)
#define NB_MATCH 235                 // tet-match probe for new tets
// K_tail block-range split
#define NB_FB    120                 // fallback blocks (scan 500 walkers each)
#define NB_ASM   235
#define FBRANGE  (TNEW / NB_FB)      // 500

// workspace layout: [0xFF-init region][rest, no init needed]
#define OFF_TKEYS    0u              // 131072*8 = 1,048,576
#define OFF_FTAB     1048576u        // 131072*8 = 1,048,576
#define OFF_NBR      2097152u        // 240000*4 =   960,000
#define FF_BYTES     3057152u        // end of 0xFF region
#define OFF_CNT      3057152u        // 2048 B: counters[0..63] + hist[0..301] (zeroed by k_front blk0)
#define OFF_TVALS    3059200u        // 524,288 (poison-safe)
#define OFF_PPRIO    3583488u        // 1,920,000 (fully written by prio2 part)
#define OFF_PRIO     5503488u        // 120,000 (fully written by fold part)
#define OFF_IDXOLD   5623488u        // 960,000 (16B aligned)
#define OFF_SSTEP    6583488u        // 240,000 (settle step per walker)
#define OFF_REM      6823488u        // 240,000
#define OFF_DEGEN    7063488u        // 240,000
#define OFF_MATCHED  7303488u        // 240,000
#define OFF_TV4      7543488u        // 2,880,000 (3 float4/tet: Tinv row + v0 comp)
#define OFF_COLD4    10423488u       // 960,000 (centroid, oel)
#define OFF_CNEW4    11383488u       // 960,000 (centroid, nel)
#define OFF_DM       12343488u       // 64-bit keyed DM face table (uninit/poison-safe)

struct P {
  const unsigned int* rawNew;
  const unsigned int* rawOld;
  const float* occ;
  const float* ncc;
  const float* verts;
  float* out;
  unsigned long long* tkeys;
  unsigned long long* ftab;
  int* counters;   // [0]=n_walk; [64..365]=hist[s] (settle-step histogram)
  int* tvals;
  int* idxOld;
  int* nbr;
  int* pprio;
  int* prio;
  int* sstep; int* rem;
  int* degen;
  int* matched;
  float4* Tv4;
  float4* cold4;
  float4* cnew4;
  unsigned long long* dm;            // (key<<18 | tet*4+local), racy last-wins
  unsigned int dmMask;
};

__device__ __forceinline__ unsigned hash64(unsigned long long k){
  k ^= k >> 33; k *= 0xff51afd7ed558ccdULL;
  k ^= k >> 33; k *= 0xc4ceb9fe1a85ec53ULL;
  k ^= k >> 33;
  return (unsigned)k;
}
__device__ __forceinline__ void cswap(int& a, int& b){ if (a > b){ int t = a; a = b; b = t; } }

__device__ __forceinline__ int detect64(const unsigned int* raw){
  unsigned acc = 0;
  const uint4* r4 = (const uint4*)raw;
  #pragma unroll
  for (int k = 0; k < 32; ++k){ uint4 v = r4[k]; acc |= (v.y | v.w); }
  return acc == 0u;
}

__device__ __forceinline__ int4 load_tet4(const unsigned int* raw, int is64, int t){
  if (is64){
    uint4 a = ((const uint4*)raw)[t * 2 + 0];
    uint4 b = ((const uint4*)raw)[t * 2 + 1];
    return make_int4((int)a.x, (int)a.z, (int)b.x, (int)b.z);
  }
  uint4 a = ((const uint4*)raw)[t];
  return make_int4((int)a.x, (int)a.y, (int)a.z, (int)a.w);
}

__device__ __forceinline__ void face_insert(unsigned long long* ftab, int* nbr,
                                            unsigned long long fkey, int t, int l){
  unsigned long long mine = (fkey << 18) | (unsigned long long)(t * 4 + l);
  unsigned slot = hash64(fkey ^ 0x9e3779b97f4a7c15ULL) & (FHSZ - 1);
  while (true){
    unsigned long long prev = atomicCAS(&ftab[slot], EMPTY64, mine);
    if (prev == EMPTY64) return;
    if ((prev >> 18) == fkey){
      int oid = (int)(prev & 0x3FFFFULL);
      nbr[t * 4 + l] = oid >> 2;
      nbr[oid] = t;
      return;
    }
    slot = (slot + 1) & (FHSZ - 1);
  }
}

__device__ __forceinline__ float min_edge_r(
    float q0x, float q0y, float q0z, float q1x, float q1y, float q1z,
    float q2x, float q2y, float q2z, float q3x, float q3y, float q3z){
  float m = 3.402823466e+38f;
  float dx, dy, dz, d;
  dx = q0x - q1x; dy = q0y - q1y; dz = q0z - q1z; d = sqrtf((dx*dx + dy*dy) + dz*dz); m = fminf(m, d);
  dx = q0x - q2x; dy = q0y - q2y; dz = q0z - q2z; d = sqrtf((dx*dx + dy*dy) + dz*dz); m = fminf(m, d);
  dx = q0x - q3x; dy = q0y - q3y; dz = q0z - q3z; d = sqrtf((dx*dx + dy*dy) + dz*dz); m = fminf(m, d);
  dx = q1x - q2x; dy = q1y - q2y; dz = q1z - q2z; d = sqrtf((dx*dx + dy*dy) + dz*dz); m = fminf(m, d);
  dx = q1x - q3x; dy = q1y - q3y; dz = q1z - q3z; d = sqrtf((dx*dx + dy*dy) + dz*dz); m = fminf(m, d);
  dx = q2x - q3x; dy = q2y - q3y; dz = q2z - q3z; d = sqrtf((dx*dx + dy*dy) + dz*dz); m = fminf(m, d);
  return m;
}

// K1: setup [0,235) | prio partial-max [235,1195) | new-geometry [1195,1430)
__global__ __launch_bounds__(256) void k_front(P p){
  __shared__ int sprio[VRANGE];
  int bb = blockIdx.x;
  if (bb < NB_SETUP){
    int t = bb * 256 + threadIdx.x;
    if (bb == 0){
      for (int j = threadIdx.x; j < 384; j += 256) p.counters[j] = 0;
    }
    if (t >= TOLD) return;
    int is64 = detect64(p.rawOld);
    int4 iv4 = load_tet4(p.rawOld, is64, t);
    int i0 = iv4.x, i1 = iv4.y, i2 = iv4.z, i3 = iv4.w;
    ((int4*)p.idxOld)[t] = iv4;

    // tet key insert; CAS winner plain-stores value, dup-key path (P~5e-8)
    // uses atomicMax. tvals poison (negative) always loses the max.
    {
      int s0 = i0, s1 = i1, s2 = i2, s3 = i3;
      cswap(s0, s1); cswap(s2, s3); cswap(s0, s2); cswap(s1, s3); cswap(s1, s2);
      unsigned long long key =
          (unsigned long long)((((long long)s0 * NVERT + s1) * NVERT + s2) * NVERT + s3);
      unsigned slot = hash64(key) & (THSZ - 1);
      while (true){
        unsigned long long prev = atomicCAS(&p.tkeys[slot], EMPTY64, key);
        if (prev == EMPTY64){ p.tvals[slot] = t; break; }
        if (prev == key){ atomicMax(&p.tvals[slot], t); break; }
        slot = (slot + 1) & (THSZ - 1);
      }
    }

    // 64-bit keyed DM face writes (racy last-wins; resolved in k_mid)
    if (p.dmMask){
      const int FO[4][3] = {{1, 2, 3}, {0, 2, 3}, {0, 1, 3}, {0, 1, 2}};
      int iv[4] = {i0, i1, i2, i3};
      #pragma unroll
      for (int l = 0; l < 4; ++l){
        int a = iv[FO[l][0]], b = iv[FO[l][1]], c = iv[FO[l][2]];
        cswap(a, b); cswap(a, c); cswap(b, c);
        unsigned long long fk = (unsigned long long)(((long long)a * NVERT + b) * NVERT + c);
        p.dm[hash64(fk) & p.dmMask] = (fk << 18) | (unsigned long long)(t * 4 + l);
      }
    }

    float q0x = p.verts[i0 * 3 + 0], q0y = p.verts[i0 * 3 + 1], q0z = p.verts[i0 * 3 + 2];
    float q1x = p.verts[i1 * 3 + 0], q1y = p.verts[i1 * 3 + 1], q1z = p.verts[i1 * 3 + 2];
    float q2x = p.verts[i2 * 3 + 0], q2y = p.verts[i2 * 3 + 1], q2z = p.verts[i2 * 3 + 2];
    float q3x = p.verts[i3 * 3 + 0], q3y = p.verts[i3 * 3 + 1], q3z = p.verts[i3 * 3 + 2];
    float e1x = q1x - q0x, e1y = q1y - q0y, e1z = q1z - q0z;
    float e2x = q2x - q0x, e2y = q2y - q0y, e2z = q2z - q0z;
    float e3x = q3x - q0x, e3y = q3y - q0y, e3z = q3z - q0z;
    float c23x = e2y * e3z - e2z * e3y;
    float c23y = e2z * e3x - e2x * e3z;
    float c23z = e2x * e3y - e2y * e3x;
    float det = e1x * c23x + e1y * c23y + e1z * c23z;
    int dg = (fabsf(det) < 1e-10f) ? 1 : 0;
    p.degen[t] = dg;
    float4 r0, r1, r2;
    if (dg){
      r0 = make_float4(1.f, 0.f, 0.f, q0x);
      r1 = make_float4(0.f, 1.f, 0.f, q0y);
      r2 = make_float4(0.f, 0.f, 1.f, q0z);
    } else {
      float inv = 1.0f / det;
      float c31x = e3y * e1z - e3z * e1y;
      float c31y = e3z * e1x - e3x * e1z;
      float c31z = e3x * e1y - e3y * e1x;
      float c12x = e1y * e2z - e1z * e2y;
      float c12y = e1z * e2x - e1x * e2z;
      float c12z = e1x * e2y - e1y * e2x;
      r0 = make_float4(c23x * inv, c23y * inv, c23z * inv, q0x);
      r1 = make_float4(c31x * inv, c31y * inv, c31z * inv, q0y);
      r2 = make_float4(c12x * inv, c12y * inv, c12z * inv, q0z);
    }
    p.Tv4[t * 3 + 0] = r0;
    p.Tv4[t * 3 + 1] = r1;
    p.Tv4[t * 3 + 2] = r2;
    float el = min_edge_r(q0x, q0y, q0z, q1x, q1y, q1z, q2x, q2y, q2z, q3x, q3y, q3z);
    p.cold4[t] = make_float4((((q0x + q1x) + q2x) + q3x) * 0.25f,
                             (((q0y + q1y) + q2y) + q3y) * 0.25f,
                             (((q0z + q1z) + q2z) + q3z) * 0.25f, el);
  } else if (bb < NB_SETUP + NB_PRIO){
    int rb = bb - NB_SETUP;
    int range = rb / NSLICE;
    int slice = rb % NSLICE;
    int base = range * VRANGE;
    for (int j = threadIdx.x; j < VRANGE; j += 256) sprio[j] = -1;
    __syncthreads();
    int is64 = detect64(p.rawOld);
    int t0 = slice * TSLICE;
    for (int t = t0 + threadIdx.x; t < t0 + TSLICE; t += 256){
      int4 iv = load_tet4(p.rawOld, is64, t);
      int v;
      v = iv.x - base; if ((unsigned)v < VRANGE) atomicMax(&sprio[v], 0 * TOLD + t);
      v = iv.y - base; if ((unsigned)v < VRANGE) atomicMax(&sprio[v], 1 * TOLD + t);
      v = iv.z - base; if ((unsigned)v < VRANGE) atomicMax(&sprio[v], 2 * TOLD + t);
      v = iv.w - base; if ((unsigned)v < VRANGE) atomicMax(&sprio[v], 3 * TOLD + t);
    }
    __syncthreads();
    for (int j = threadIdx.x; j < VRANGE; j += 256)
      p.pprio[slice * NVERT + base + j] = sprio[j];
  } else {
    int n = (bb - NB_SETUP - NB_PRIO) * 256 + threadIdx.x;
    if (n >= TNEW) return;
    int is64 = detect64(p.rawNew);
    int4 ni = load_tet4(p.rawNew, is64, n);
    float q0x = p.verts[ni.x * 3 + 0], q0y = p.verts[ni.x * 3 + 1], q0z = p.verts[ni.x * 3 + 2];
    float q1x = p.verts[ni.y * 3 + 0], q1y = p.verts[ni.y * 3 + 1], q1z = p.verts[ni.y * 3 + 2];
    float q2x = p.verts[ni.z * 3 + 0], q2y = p.verts[ni.z * 3 + 1], q2z = p.verts[ni.z * 3 + 2];
    float q3x = p.verts[ni.w * 3 + 0], q3y = p.verts[ni.w * 3 + 1], q3z = p.verts[ni.w * 3 + 2];
    float el = min_edge_r(q0x, q0y, q0z, q1x, q1y, q1z, q2x, q2y, q2z, q3x, q3y, q3z);
    p.cnew4[n] = make_float4((((q0x + q1x) + q2x) + q3x) * 0.25f,
                             (((q0y + q1y) + q2y) + q3y) * 0.25f,
                             (((q0z + q1z) + q2z) + q3z) * 0.25f, el);
  }
}

// K2: face resolve [0,938) + pprio fold [938,1056) + new-tet match probe [1056,1291)
__global__ __launch_bounds__(256) void k_mid(P p){
  int bb = blockIdx.x;
  if (bb < NB_FACE){
    int i = bb * 256 + threadIdx.x;
    if (i >= TOLD * 4) return;
    int t = i >> 2, l = i & 3;
    int4 iv4 = ((const int4*)p.idxOld)[t];
    int iv[4] = {iv4.x, iv4.y, iv4.z, iv4.w};
    const int FO[4][3] = {{1, 2, 3}, {0, 2, 3}, {0, 1, 3}, {0, 1, 2}};
    int a = iv[FO[l][0]], b = iv[FO[l][1]], c = iv[FO[l][2]];
    cswap(a, b); cswap(a, c); cswap(b, c);
    unsigned long long fk = (unsigned long long)(((long long)a * NVERT + b) * NVERT + c);
    if (p.dmMask){
      unsigned long long mine = (fk << 18) | (unsigned long long)i;
      unsigned long long got = p.dm[hash64(fk) & p.dmMask];
      if (got == mine) return;                       // self-winner; partner links both
      if ((got >> 18) == fk){                        // key-verified partner
        int wid = (int)(got & 0x3FFFFULL);
        p.nbr[i] = wid >> 2;
        p.nbr[wid] = t;
        return;
      }
    }
    face_insert(p.ftab, p.nbr, fk, t, l);            // bucket collision: exact CAS
  } else if (bb < NB_FACE + NB_FOLD){
    int v = (bb - NB_FACE) * 256 + threadIdx.x;
    if (v >= NVERT) return;
    int pr = -1;
    #pragma unroll
    for (int s = 0; s < NSLICE; ++s) pr = max(pr, p.pprio[s * NVERT + v]);
    p.prio[v] = pr;
  } else {
    int n = (bb - NB_FACE - NB_FOLD) * 256 + threadIdx.x;
    if (n >= TNEW) return;
    int is64 = detect64(p.rawNew);
    int4 ni = load_tet4(p.rawNew, is64, n);
    int s0 = ni.x, s1 = ni.y, s2 = ni.z, s3 = ni.w;
    cswap(s0, s1); cswap(s2, s3); cswap(s0, s2); cswap(s1, s3); cswap(s1, s2);
    unsigned long long key =
        (unsigned long long)((((long long)s0 * NVERT + s1) * NVERT + s2) * NVERT + s3);
    int m = -1;
    unsigned slot = hash64(key) & (THSZ - 1);
    while (true){
      unsigned long long k = p.tkeys[slot];
      if (k == EMPTY64) break;
      if (k == key){ m = p.tvals[slot]; break; }
      slot = (slot + 1) & (THSZ - 1);
    }
    p.matched[n] = m;
  }
}

// K3: per-walker LOCAL walk to settlement. The reference while-loop's only
// cross-walker coupling is the stop step S = min{k: count_k < thr}; count_k
// depends only on per-walker settle steps s_n, which we histogram here.
// Walkers with s_n <= S keep their settled rem; s_n > S get fallback (k_tail).
__global__ __launch_bounds__(256) void k_walkall(P p){
  int n = blockIdx.x * blockDim.x + threadIdx.x;
  if (n >= TNEW) return;
  if (p.matched[n] >= 0) return;
  atomicAdd(&p.counters[0], 1);                      // n_walk (wave-coalesced)
  int is64 = detect64(p.rawNew);
  int i0 = is64 ? (int)((const long long*)p.rawNew)[n * 4] : ((const int*)p.rawNew)[n * 4];
  int pr = p.prio[i0];
  int c = (pr >= 0) ? (pr % TOLD) : 0;               // seed
  float4 cn = p.cnew4[n];
  int s = MAXSTEPS + 1;                              // 301 = never settles
  for (int k = 1; k <= MAXSTEPS; ++k){
    float4 r0 = p.Tv4[c * 3 + 0];
    float4 r1 = p.Tv4[c * 3 + 1];
    float4 r2 = p.Tv4[c * 3 + 2];
    float rx = cn.x - r0.w, ry = cn.y - r1.w, rz = cn.z - r2.w;
    float b0 = r0.x * rx + r0.y * ry + r0.z * rz;
    float b1 = r1.x * rx + r1.y * ry + r1.z * rz;
    float b2 = r2.x * rx + r2.y * ry + r2.z * rz;
    float a0 = 1.0f - (b0 + b1 + b2);
    float ab[4] = {a0, b0, b1, b2};
    int amin = 0; float mn = ab[0];
    for (int j = 1; j < 4; ++j){ if (ab[j] < mn){ mn = ab[j]; amin = j; } }
    if (mn >= -0.0001f){ p.rem[n] = c; s = k; break; }          // converged
    int nb = p.degen[c] ? -1 : p.nbr[c * 4 + amin];
    if (nb < 0){ p.rem[n] = c; s = k; break; }                  // boundary
    c = nb;
  }
  p.sstep[n] = s;
  atomicAdd(&p.counters[64 + s], 1);                 // hist (wave-coalesced when uniform)
}

// Exact loop-exit step from the settle-step histogram:
// count_k = nw - sum_{j<=k} hist[j]; S = first k in [0,300] with count_k < thr
// (thr = max(100, nw/1000)), else 300 (MAXSTEPS bound).
__device__ __forceinline__ int compute_S(const int* counters){
  int nw = counters[0];
  int thr = max(100, nw / 1000);
  if (nw < thr) return 0;
  int cnt = nw;
  for (int k = 1; k <= MAXSTEPS; ++k){
    cnt -= counters[64 + k];
    if (cnt < thr) return k;
  }
  return MAXSTEPS;
}

// Per-walker output assembly. Fast path when all 5 candidates coincide.
__device__ __forceinline__ void assemble_walker(const P& p, int n, int m, int remap){
  int cds[5];
  if (m >= 0){
    cds[0] = cds[1] = cds[2] = cds[3] = cds[4] = m;
  } else {
    cds[0] = remap;
    int dg = p.degen[remap];
    int4 nb4 = ((const int4*)p.nbr)[remap];
    int nbl[4] = {nb4.x, nb4.y, nb4.z, nb4.w};
    for (int l = 0; l < 4; ++l){
      int fb = dg ? -1 : nbl[l];
      cds[1 + l] = (fb >= 0) ? fb : remap;
    }
  }
  bool same = (cds[1] == cds[0]) & (cds[2] == cds[0]) &
              (cds[3] == cds[0]) & (cds[4] == cds[0]);
  int is64 = detect64(p.rawNew);
  int4 ni = load_tet4(p.rawNew, is64, n);
  float nc0 = p.ncc[n * 3 + 0], nc1 = p.ncc[n * 3 + 1], nc2 = p.ncc[n * 3 + 2];
  float nelv = fmaxf(p.cnew4[n].w, 1e-8f);
  if (same){
    int ct = cds[0];
    int4 cv = ((const int4*)p.idxOld)[ct];
    int ov = 0;
    ov += (cv.x == ni.x || cv.x == ni.y || cv.x == ni.z || cv.x == ni.w) ? 1 : 0;
    ov += (cv.y == ni.x || cv.y == ni.y || cv.y == ni.z || cv.y == ni.w) ? 1 : 0;
    ov += (cv.z == ni.x || cv.z == ni.y || cv.z == ni.z || cv.z == ni.w) ? 1 : 0;
    ov += (cv.w == ni.x || cv.w == ni.y || cv.w == ni.z || cv.w == ni.w) ? 1 : 0;
    float d0 = p.occ[ct * 3 + 0] - nc0;
    float d1 = p.occ[ct * 3 + 1] - nc1;
    float d2 = p.occ[ct * 3 + 2] - nc2;
    float ccd2 = (d0 * d0 + d1 * d1) + d2 * d2;
    float raw = expf((float)ov * 2.0f) / (ccd2 + 1e-8f);
    float rsum = 0.0f;
    rsum += raw; rsum += raw; rsum += raw; rsum += raw; rsum += raw;
    float wgt = raw / rsum;
    float ds = p.cold4[ct].w / nelv;
    ds = fminf(fmaxf(ds, 0.1f), 10.0f);
    float cf = (float)ct;
    for (int c = 0; c < 5; ++c){
      p.out[n * 5 + c] = cf;
      p.out[TNEW * 5 + n * 5 + c] = wgt;
      p.out[2 * TNEW * 5 + n * 5 + c] = ds;
    }
    return;
  }
  float raws[5]; float rsum = 0.0f;
  float oels[5];
  for (int c = 0; c < 5; ++c){
    int ct = cds[c];
    int4 cv = ((const int4*)p.idxOld)[ct];
    int ov = 0;
    ov += (cv.x == ni.x || cv.x == ni.y || cv.x == ni.z || cv.x == ni.w) ? 1 : 0;
    ov += (cv.y == ni.x || cv.y == ni.y || cv.y == ni.z || cv.y == ni.w) ? 1 : 0;
    ov += (cv.z == ni.x || cv.z == ni.y || cv.z == ni.z || cv.z == ni.w) ? 1 : 0;
    ov += (cv.w == ni.x || cv.w == ni.y || cv.w == ni.z || cv.w == ni.w) ? 1 : 0;
    float d0 = p.occ[ct * 3 + 0] - nc0;
    float d1 = p.occ[ct * 3 + 1] - nc1;
    float d2 = p.occ[ct * 3 + 2] - nc2;
    float ccd2 = (d0 * d0 + d1 * d1) + d2 * d2;
    float raw = expf((float)ov * 2.0f) / (ccd2 + 1e-8f);
    raws[c] = raw; rsum += raw;
    oels[c] = p.cold4[ct].w;
  }
  for (int c = 0; c < 5; ++c){
    p.out[n * 5 + c] = (float)cds[c];
    p.out[TNEW * 5 + n * 5 + c] = raws[c] / rsum;
    float ds = oels[c] / nelv;
    ds = fminf(fmaxf(ds, 0.1f), 10.0f);
    p.out[2 * TNEW * 5 + n * 5 + c] = ds;
  }
}

// K4: every block derives S from the histogram (exact, wave-uniform reads).
// Blocks [0,120): scan own 500-walker slice for fallback-owned (sstep > S),
// collect hits in LDS, cooperative nearest-centroid + inline assemble.
// Blocks [120,355): assemble all other walkers. Exact disjoint partition.
__global__ __launch_bounds__(256) void k_tail(P p){
  __shared__ float sd[256];
  __shared__ int si[256];
  __shared__ int s_hits[256];
  __shared__ int s_nhits;
  __shared__ int s_S;
  if (threadIdx.x == 0) s_S = compute_S(p.counters);
  __syncthreads();
  int S = s_S;
  int bb = blockIdx.x;
  if (bb < NB_FB){
    int base = bb * FBRANGE;
    for (int chunk = base; chunk < base + FBRANGE; chunk += 256){
      if (threadIdx.x == 0) s_nhits = 0;
      __syncthreads();
      int n = chunk + threadIdx.x;
      if (n < base + FBRANGE && n < TNEW){
        if (p.matched[n] < 0 && p.sstep[n] > S)
          s_hits[atomicAdd(&s_nhits, 1)] = n;
      }
      __syncthreads();
      int nh = s_nhits;
      for (int h = 0; h < nh; ++h){
        int n2 = s_hits[h];
        float4 cn = p.cnew4[n2];
        float cx = cn.x, cy = cn.y, cz = cn.z;
        float p2 = (cx * cx + cy * cy) + cz * cz;
        float bd = 3.402823466e+38f; int bi = 0;
        for (int j = threadIdx.x; j < TOLD; j += 256){
          float4 oc = p.cold4[j];
          float dot = (cx * oc.x + cy * oc.y) + cz * oc.z;
          float c2 = (oc.x * oc.x + oc.y * oc.y) + oc.z * oc.z;
          float d = (p2 - 2.0f * dot) + c2;
          if (d < bd || (d == bd && j < bi)){ bd = d; bi = j; }
        }
        sd[threadIdx.x] = bd; si[threadIdx.x] = bi;
        __syncthreads();
        for (int s = 128; s > 0; s >>= 1){
          if ((int)threadIdx.x < s){
            float od = sd[threadIdx.x + s]; int oi = si[threadIdx.x + s];
            if (od < sd[threadIdx.x] || (od == sd[threadIdx.x] && oi < si[threadIdx.x])){
              sd[threadIdx.x] = od; si[threadIdx.x] = oi;
            }
          }
          __syncthreads();
        }
        if (threadIdx.x == 0){
          int r = si[0];
          if (r < 0) r = 0; if (r > TOLD - 1) r = TOLD - 1;
          assemble_walker(p, n2, -1, r);
        }
        __syncthreads();
      }
      __syncthreads();
    }
  } else {
    int n = (bb - NB_FB) * 256 + threadIdx.x;
    if (n >= TNEW) return;
    int m = p.matched[n];
    int remap = 0;
    if (m < 0){
      if (p.sstep[n] > S) return;                    // fallback blocks own it
      remap = p.rem[n];
    }
    assemble_walker(p, n, m, remap);
  }
}

extern "C" void kernel_launch(void* const* d_in, const int* in_sizes, int n_in,
                              void* d_out, int out_size, void* d_ws, size_t ws_size,
                              hipStream_t stream) {
  char* w = (char*)d_ws;
  P p;
  p.rawNew = (const unsigned int*)d_in[0];
  p.rawOld = (const unsigned int*)d_in[1];
  p.occ    = (const float*)d_in[2];
  p.ncc    = (const float*)d_in[3];
  p.verts  = (const float*)d_in[4];
  p.out    = (float*)d_out;
  p.tkeys    = (unsigned long long*)(w + OFF_TKEYS);
  p.ftab     = (unsigned long long*)(w + OFF_FTAB);
  p.nbr      = (int*)(w + OFF_NBR);
  p.counters = (int*)(w + OFF_CNT);
  p.tvals    = (int*)(w + OFF_TVALS);
  p.pprio    = (int*)(w + OFF_PPRIO);
  p.prio     = (int*)(w + OFF_PRIO);
  p.idxOld   = (int*)(w + OFF_IDXOLD);
  p.sstep    = (int*)(w + OFF_SSTEP);
  p.rem      = (int*)(w + OFF_REM);
  p.degen    = (int*)(w + OFF_DEGEN);
  p.matched  = (int*)(w + OFF_MATCHED);
  p.Tv4      = (float4*)(w + OFF_TV4);
  p.cold4    = (float4*)(w + OFF_COLD4);
  p.cnew4    = (float4*)(w + OFF_CNEW4);
  p.dm       = (unsigned long long*)(w + OFF_DM);
  size_t avail = (ws_size > (size_t)OFF_DM) ? ws_size - (size_t)OFF_DM : 0;
  unsigned dmMask = 0;
  for (int bshift = 21; bshift >= 16; --bshift){
    if (avail >= ((size_t)8 << bshift)){ dmMask = (1u << bshift) - 1u; break; }
  }
  p.dmMask = dmMask;

  hipMemsetAsync(w, 0xFF, FF_BYTES, stream);
  hipLaunchKernelGGL(k_front,   dim3(NB_SETUP + NB_PRIO + NB_NEWG), dim3(256), 0, stream, p);
  hipLaunchKernelGGL(k_mid,     dim3(NB_FACE + NB_FOLD + NB_MATCH), dim3(256), 0, stream, p);
  hipLaunchKernelGGL(k_walkall, dim3((TNEW + 255) / 256), dim3(256), 0, stream, p);
  hipLaunchKernelGGL(k_tail,    dim3(NB_FB + NB_ASM), dim3(256), 0, stream, p);
}

// Round 12
// 115.333 us; speedup vs baseline: 6.9230x; 6.9230x over previous
//
#include <hip/hip_runtime.h>

#pragma clang fp contract(off)

#define TOLD 60000
#define TNEW 60000
#define NVERT 30000
#define MAXSTEPS 300
#define THSZ 131072                  // tet-key hash slots (exact, CAS)
#define FHSZ 131072                  // exact CAS face table (DM-collision fallback only)
#define EMPTY64 0xFFFFFFFFFFFFFFFFULL
#define NWGR 60                      // prio vertex ranges (500 verts each)
#define VRANGE 500
#define NSLICE 16                    // prio tet slices
#define TSLICE (TOLD / NSLICE)       // 3750

// K1 block-range split
#define NB_SETUP 235                 // ceil(60000/256)
#define NB_PRIO  (NWGR * NSLICE)     // 960
#define NB_NEWG  235
// K2 block-range split
#define NB_FACE  938                 // ceil(240000/256)
#define NB_FOLD  118                 // ceil(30000/256)
#define NB_MATCH 235                 // tet-match probe for new tets
// K_tail block-range split
#define NB_FB    120                 // fallback blocks (scan 500 walkers each)
#define NB_ASM   235
#define FBRANGE  (TNEW / NB_FB)      // 500

// workspace layout: [0xFF-init region][rest, no init needed]
#define OFF_TKEYS    0u              // 131072*8 = 1,048,576
#define OFF_FTAB     1048576u        // 131072*8 = 1,048,576
#define OFF_NBR      2097152u        // 240000*4 =   960,000
#define FF_BYTES     3057152u        // end of 0xFF region
#define OFF_CNT      3057152u        // 2048 B: counters[0..63] + hist[64..365] (zeroed by k_front blk0)
#define OFF_TVALS    3059200u        // 524,288 (poison-safe)
#define OFF_PPRIO    3583488u        // 1,920,000 (fully written by prio2 part)
#define OFF_PRIO     5503488u        // 120,000 (fully written by fold part)
#define OFF_IDXOLD   5623488u        // 960,000 (16B aligned)
#define OFF_SSTEP    6583488u        // 240,000 (settle step per walker)
#define OFF_REM      6823488u        // 240,000
#define OFF_DEGEN    7063488u        // 240,000
#define OFF_MATCHED  7303488u        // 240,000
#define OFF_TV4      7543488u        // 2,880,000 (3 float4/tet: Tinv row + v0 comp)
#define OFF_COLD4    10423488u       // 960,000 (centroid, oel)
#define OFF_CNEW4    11383488u       // 960,000 (centroid, nel)
#define OFF_DM       12343488u       // 64-bit keyed DM face table (uninit/poison-safe)

struct P {
  const unsigned int* rawNew;
  const unsigned int* rawOld;
  const float* occ;
  const float* ncc;
  const float* verts;
  float* out;
  unsigned long long* tkeys;
  unsigned long long* ftab;
  int* counters;   // [0]=n_walk; [64..365]=hist[s] (settle-step histogram)
  int* tvals;
  int* idxOld;
  int* nbr;
  int* pprio;
  int* prio;
  int* sstep; int* rem;
  int* degen;
  int* matched;
  float4* Tv4;
  float4* cold4;
  float4* cnew4;
  unsigned long long* dm;            // (key<<18 | tet*4+local), racy last-wins
  unsigned int dmMask;
};

__device__ __forceinline__ unsigned hash64(unsigned long long k){
  k ^= k >> 33; k *= 0xff51afd7ed558ccdULL;
  k ^= k >> 33; k *= 0xc4ceb9fe1a85ec53ULL;
  k ^= k >> 33;
  return (unsigned)k;
}
__device__ __forceinline__ void cswap(int& a, int& b){ if (a > b){ int t = a; a = b; b = t; } }

__device__ __forceinline__ int detect64(const unsigned int* raw){
  unsigned acc = 0;
  const uint4* r4 = (const uint4*)raw;
  #pragma unroll
  for (int k = 0; k < 32; ++k){ uint4 v = r4[k]; acc |= (v.y | v.w); }
  return acc == 0u;
}

__device__ __forceinline__ int4 load_tet4(const unsigned int* raw, int is64, int t){
  if (is64){
    uint4 a = ((const uint4*)raw)[t * 2 + 0];
    uint4 b = ((const uint4*)raw)[t * 2 + 1];
    return make_int4((int)a.x, (int)a.z, (int)b.x, (int)b.z);
  }
  uint4 a = ((const uint4*)raw)[t];
  return make_int4((int)a.x, (int)a.y, (int)a.z, (int)a.w);
}

__device__ __forceinline__ void face_insert(unsigned long long* ftab, int* nbr,
                                            unsigned long long fkey, int t, int l){
  unsigned long long mine = (fkey << 18) | (unsigned long long)(t * 4 + l);
  unsigned slot = hash64(fkey ^ 0x9e3779b97f4a7c15ULL) & (FHSZ - 1);
  while (true){
    unsigned long long prev = atomicCAS(&ftab[slot], EMPTY64, mine);
    if (prev == EMPTY64) return;
    if ((prev >> 18) == fkey){
      int oid = (int)(prev & 0x3FFFFULL);
      nbr[t * 4 + l] = oid >> 2;
      nbr[oid] = t;
      return;
    }
    slot = (slot + 1) & (FHSZ - 1);
  }
}

__device__ __forceinline__ float min_edge_r(
    float q0x, float q0y, float q0z, float q1x, float q1y, float q1z,
    float q2x, float q2y, float q2z, float q3x, float q3y, float q3z){
  float m = 3.402823466e+38f;
  float dx, dy, dz, d;
  dx = q0x - q1x; dy = q0y - q1y; dz = q0z - q1z; d = sqrtf((dx*dx + dy*dy) + dz*dz); m = fminf(m, d);
  dx = q0x - q2x; dy = q0y - q2y; dz = q0z - q2z; d = sqrtf((dx*dx + dy*dy) + dz*dz); m = fminf(m, d);
  dx = q0x - q3x; dy = q0y - q3y; dz = q0z - q3z; d = sqrtf((dx*dx + dy*dy) + dz*dz); m = fminf(m, d);
  dx = q1x - q2x; dy = q1y - q2y; dz = q1z - q2z; d = sqrtf((dx*dx + dy*dy) + dz*dz); m = fminf(m, d);
  dx = q1x - q3x; dy = q1y - q3y; dz = q1z - q3z; d = sqrtf((dx*dx + dy*dy) + dz*dz); m = fminf(m, d);
  dx = q2x - q3x; dy = q2y - q3y; dz = q2z - q3z; d = sqrtf((dx*dx + dy*dy) + dz*dz); m = fminf(m, d);
  return m;
}

// K1: setup [0,235) | prio partial-max [235,1195) | new-geometry [1195,1430)
__global__ __launch_bounds__(256) void k_front(P p){
  __shared__ int sprio[VRANGE];
  int bb = blockIdx.x;
  if (bb < NB_SETUP){
    int t = bb * 256 + threadIdx.x;
    if (bb == 0){
      for (int j = threadIdx.x; j < 384; j += 256) p.counters[j] = 0;
    }
    if (t >= TOLD) return;
    int is64 = detect64(p.rawOld);
    int4 iv4 = load_tet4(p.rawOld, is64, t);
    int i0 = iv4.x, i1 = iv4.y, i2 = iv4.z, i3 = iv4.w;
    ((int4*)p.idxOld)[t] = iv4;

    // tet key insert; CAS winner plain-stores value, dup-key path (P~5e-8)
    // uses atomicMax. tvals poison (negative) always loses the max.
    {
      int s0 = i0, s1 = i1, s2 = i2, s3 = i3;
      cswap(s0, s1); cswap(s2, s3); cswap(s0, s2); cswap(s1, s3); cswap(s1, s2);
      unsigned long long key =
          (unsigned long long)((((long long)s0 * NVERT + s1) * NVERT + s2) * NVERT + s3);
      unsigned slot = hash64(key) & (THSZ - 1);
      while (true){
        unsigned long long prev = atomicCAS(&p.tkeys[slot], EMPTY64, key);
        if (prev == EMPTY64){ p.tvals[slot] = t; break; }
        if (prev == key){ atomicMax(&p.tvals[slot], t); break; }
        slot = (slot + 1) & (THSZ - 1);
      }
    }

    // 64-bit keyed DM face writes (racy last-wins; resolved in k_mid)
    if (p.dmMask){
      const int FO[4][3] = {{1, 2, 3}, {0, 2, 3}, {0, 1, 3}, {0, 1, 2}};
      int iv[4] = {i0, i1, i2, i3};
      #pragma unroll
      for (int l = 0; l < 4; ++l){
        int a = iv[FO[l][0]], b = iv[FO[l][1]], c = iv[FO[l][2]];
        cswap(a, b); cswap(a, c); cswap(b, c);
        unsigned long long fk = (unsigned long long)(((long long)a * NVERT + b) * NVERT + c);
        p.dm[hash64(fk) & p.dmMask] = (fk << 18) | (unsigned long long)(t * 4 + l);
      }
    }

    float q0x = p.verts[i0 * 3 + 0], q0y = p.verts[i0 * 3 + 1], q0z = p.verts[i0 * 3 + 2];
    float q1x = p.verts[i1 * 3 + 0], q1y = p.verts[i1 * 3 + 1], q1z = p.verts[i1 * 3 + 2];
    float q2x = p.verts[i2 * 3 + 0], q2y = p.verts[i2 * 3 + 1], q2z = p.verts[i2 * 3 + 2];
    float q3x = p.verts[i3 * 3 + 0], q3y = p.verts[i3 * 3 + 1], q3z = p.verts[i3 * 3 + 2];
    float e1x = q1x - q0x, e1y = q1y - q0y, e1z = q1z - q0z;
    float e2x = q2x - q0x, e2y = q2y - q0y, e2z = q2z - q0z;
    float e3x = q3x - q0x, e3y = q3y - q0y, e3z = q3z - q0z;
    float c23x = e2y * e3z - e2z * e3y;
    float c23y = e2z * e3x - e2x * e3z;
    float c23z = e2x * e3y - e2y * e3x;
    float det = e1x * c23x + e1y * c23y + e1z * c23z;
    int dg = (fabsf(det) < 1e-10f) ? 1 : 0;
    p.degen[t] = dg;
    float4 r0, r1, r2;
    if (dg){
      r0 = make_float4(1.f, 0.f, 0.f, q0x);
      r1 = make_float4(0.f, 1.f, 0.f, q0y);
      r2 = make_float4(0.f, 0.f, 1.f, q0z);
    } else {
      float inv = 1.0f / det;
      float c31x = e3y * e1z - e3z * e1y;
      float c31y = e3z * e1x - e3x * e1z;
      float c31z = e3x * e1y - e3y * e1x;
      float c12x = e1y * e2z - e1z * e2y;
      float c12y = e1z * e2x - e1x * e2z;
      float c12z = e1x * e2y - e1y * e2x;
      r0 = make_float4(c23x * inv, c23y * inv, c23z * inv, q0x);
      r1 = make_float4(c31x * inv, c31y * inv, c31z * inv, q0y);
      r2 = make_float4(c12x * inv, c12y * inv, c12z * inv, q0z);
    }
    p.Tv4[t * 3 + 0] = r0;
    p.Tv4[t * 3 + 1] = r1;
    p.Tv4[t * 3 + 2] = r2;
    float el = min_edge_r(q0x, q0y, q0z, q1x, q1y, q1z, q2x, q2y, q2z, q3x, q3y, q3z);
    p.cold4[t] = make_float4((((q0x + q1x) + q2x) + q3x) * 0.25f,
                             (((q0y + q1y) + q2y) + q3y) * 0.25f,
                             (((q0z + q1z) + q2z) + q3z) * 0.25f, el);
  } else if (bb < NB_SETUP + NB_PRIO){
    int rb = bb - NB_SETUP;
    int range = rb / NSLICE;
    int slice = rb % NSLICE;
    int base = range * VRANGE;
    for (int j = threadIdx.x; j < VRANGE; j += 256) sprio[j] = -1;
    __syncthreads();
    int is64 = detect64(p.rawOld);
    int t0 = slice * TSLICE;
    for (int t = t0 + threadIdx.x; t < t0 + TSLICE; t += 256){
      int4 iv = load_tet4(p.rawOld, is64, t);
      int v;
      v = iv.x - base; if ((unsigned)v < VRANGE) atomicMax(&sprio[v], 0 * TOLD + t);
      v = iv.y - base; if ((unsigned)v < VRANGE) atomicMax(&sprio[v], 1 * TOLD + t);
      v = iv.z - base; if ((unsigned)v < VRANGE) atomicMax(&sprio[v], 2 * TOLD + t);
      v = iv.w - base; if ((unsigned)v < VRANGE) atomicMax(&sprio[v], 3 * TOLD + t);
    }
    __syncthreads();
    for (int j = threadIdx.x; j < VRANGE; j += 256)
      p.pprio[slice * NVERT + base + j] = sprio[j];
  } else {
    int n = (bb - NB_SETUP - NB_PRIO) * 256 + threadIdx.x;
    if (n >= TNEW) return;
    int is64 = detect64(p.rawNew);
    int4 ni = load_tet4(p.rawNew, is64, n);
    float q0x = p.verts[ni.x * 3 + 0], q0y = p.verts[ni.x * 3 + 1], q0z = p.verts[ni.x * 3 + 2];
    float q1x = p.verts[ni.y * 3 + 0], q1y = p.verts[ni.y * 3 + 1], q1z = p.verts[ni.y * 3 + 2];
    float q2x = p.verts[ni.z * 3 + 0], q2y = p.verts[ni.z * 3 + 1], q2z = p.verts[ni.z * 3 + 2];
    float q3x = p.verts[ni.w * 3 + 0], q3y = p.verts[ni.w * 3 + 1], q3z = p.verts[ni.w * 3 + 2];
    float el = min_edge_r(q0x, q0y, q0z, q1x, q1y, q1z, q2x, q2y, q2z, q3x, q3y, q3z);
    p.cnew4[n] = make_float4((((q0x + q1x) + q2x) + q3x) * 0.25f,
                             (((q0y + q1y) + q2y) + q3y) * 0.25f,
                             (((q0z + q1z) + q2z) + q3z) * 0.25f, el);
  }
}

// K2: face resolve [0,938) + pprio fold [938,1056) + new-tet match probe [1056,1291)
__global__ __launch_bounds__(256) void k_mid(P p){
  int bb = blockIdx.x;
  if (bb < NB_FACE){
    int i = bb * 256 + threadIdx.x;
    if (i >= TOLD * 4) return;
    int t = i >> 2, l = i & 3;
    int4 iv4 = ((const int4*)p.idxOld)[t];
    int iv[4] = {iv4.x, iv4.y, iv4.z, iv4.w};
    const int FO[4][3] = {{1, 2, 3}, {0, 2, 3}, {0, 1, 3}, {0, 1, 2}};
    int a = iv[FO[l][0]], b = iv[FO[l][1]], c = iv[FO[l][2]];
    cswap(a, b); cswap(a, c); cswap(b, c);
    unsigned long long fk = (unsigned long long)(((long long)a * NVERT + b) * NVERT + c);
    if (p.dmMask){
      unsigned long long mine = (fk << 18) | (unsigned long long)i;
      unsigned long long got = p.dm[hash64(fk) & p.dmMask];
      if (got == mine) return;                       // self-winner; partner links both
      if ((got >> 18) == fk){                        // key-verified partner
        int wid = (int)(got & 0x3FFFFULL);
        p.nbr[i] = wid >> 2;
        p.nbr[wid] = t;
        return;
      }
    }
    face_insert(p.ftab, p.nbr, fk, t, l);            // bucket collision: exact CAS
  } else if (bb < NB_FACE + NB_FOLD){
    int v = (bb - NB_FACE) * 256 + threadIdx.x;
    if (v >= NVERT) return;
    int pr = -1;
    #pragma unroll
    for (int s = 0; s < NSLICE; ++s) pr = max(pr, p.pprio[s * NVERT + v]);
    p.prio[v] = pr;
  } else {
    int n = (bb - NB_FACE - NB_FOLD) * 256 + threadIdx.x;
    if (n >= TNEW) return;
    int is64 = detect64(p.rawNew);
    int4 ni = load_tet4(p.rawNew, is64, n);
    int s0 = ni.x, s1 = ni.y, s2 = ni.z, s3 = ni.w;
    cswap(s0, s1); cswap(s2, s3); cswap(s0, s2); cswap(s1, s3); cswap(s1, s2);
    unsigned long long key =
        (unsigned long long)((((long long)s0 * NVERT + s1) * NVERT + s2) * NVERT + s3);
    int m = -1;
    unsigned slot = hash64(key) & (THSZ - 1);
    while (true){
      unsigned long long k = p.tkeys[slot];
      if (k == EMPTY64) break;
      if (k == key){ m = p.tvals[slot]; break; }
      slot = (slot + 1) & (THSZ - 1);
    }
    p.matched[n] = m;
  }
}

// K3: per-walker LOCAL walk to settlement, with BLOCK-LOCAL LDS histogram.
// (Round-11 lesson: data-dependent global atomics to one hot line serialize
// at ~28 cyc/RMW — 60k of them was 692 us. LDS aggregation + per-block flush
// reduces global RMWs to ~500 total.)
__global__ __launch_bounds__(256) void k_walkall(P p){
  __shared__ int s_hist[MAXSTEPS + 2];               // bins 0..301
  __shared__ int s_nw;
  for (int j = threadIdx.x; j < MAXSTEPS + 2; j += 256) s_hist[j] = 0;
  if (threadIdx.x == 0) s_nw = 0;
  __syncthreads();
  int n = blockIdx.x * blockDim.x + threadIdx.x;
  if (n < TNEW && p.matched[n] < 0){
    atomicAdd(&s_nw, 1);                             // LDS
    int is64 = detect64(p.rawNew);
    int i0 = is64 ? (int)((const long long*)p.rawNew)[n * 4] : ((const int*)p.rawNew)[n * 4];
    int pr = p.prio[i0];
    int c = (pr >= 0) ? (pr % TOLD) : 0;             // seed
    float4 cn = p.cnew4[n];
    int s = MAXSTEPS + 1;                            // 301 = never settles
    for (int k = 1; k <= MAXSTEPS; ++k){
      float4 r0 = p.Tv4[c * 3 + 0];
      float4 r1 = p.Tv4[c * 3 + 1];
      float4 r2 = p.Tv4[c * 3 + 2];
      float rx = cn.x - r0.w, ry = cn.y - r1.w, rz = cn.z - r2.w;
      float b0 = r0.x * rx + r0.y * ry + r0.z * rz;
      float b1 = r1.x * rx + r1.y * ry + r1.z * rz;
      float b2 = r2.x * rx + r2.y * ry + r2.z * rz;
      float a0 = 1.0f - (b0 + b1 + b2);
      float ab[4] = {a0, b0, b1, b2};
      int amin = 0; float mn = ab[0];
      for (int j = 1; j < 4; ++j){ if (ab[j] < mn){ mn = ab[j]; amin = j; } }
      if (mn >= -0.0001f){ p.rem[n] = c; s = k; break; }        // converged
      int nb = p.degen[c] ? -1 : p.nbr[c * 4 + amin];
      if (nb < 0){ p.rem[n] = c; s = k; break; }                // boundary
      c = nb;
    }
    p.sstep[n] = s;
    atomicAdd(&s_hist[s], 1);                        // LDS
  }
  __syncthreads();
  if (threadIdx.x == 0 && s_nw) atomicAdd(&p.counters[0], s_nw);
  for (int j = threadIdx.x; j < MAXSTEPS + 2; j += 256){
    int v = s_hist[j];
    if (v) atomicAdd(&p.counters[64 + j], v);        // ~1-2 nonzero bins/block
  }
}

// Exact loop-exit step from the settle-step histogram:
// count_k = nw - sum_{j<=k} hist[j]; S = first k in [0,300] with count_k < thr
// (thr = max(100, nw/1000)), else 300 (MAXSTEPS bound).
__device__ __forceinline__ int compute_S(const int* counters){
  int nw = counters[0];
  int thr = max(100, nw / 1000);
  if (nw < thr) return 0;
  int cnt = nw;
  for (int k = 1; k <= MAXSTEPS; ++k){
    cnt -= counters[64 + k];
    if (cnt < thr) return k;
  }
  return MAXSTEPS;
}

// Per-walker output assembly. Fast path when all 5 candidates coincide.
__device__ __forceinline__ void assemble_walker(const P& p, int n, int m, int remap){
  int cds[5];
  if (m >= 0){
    cds[0] = cds[1] = cds[2] = cds[3] = cds[4] = m;
  } else {
    cds[0] = remap;
    int dg = p.degen[remap];
    int4 nb4 = ((const int4*)p.nbr)[remap];
    int nbl[4] = {nb4.x, nb4.y, nb4.z, nb4.w};
    for (int l = 0; l < 4; ++l){
      int fb = dg ? -1 : nbl[l];
      cds[1 + l] = (fb >= 0) ? fb : remap;
    }
  }
  bool same = (cds[1] == cds[0]) & (cds[2] == cds[0]) &
              (cds[3] == cds[0]) & (cds[4] == cds[0]);
  int is64 = detect64(p.rawNew);
  int4 ni = load_tet4(p.rawNew, is64, n);
  float nc0 = p.ncc[n * 3 + 0], nc1 = p.ncc[n * 3 + 1], nc2 = p.ncc[n * 3 + 2];
  float nelv = fmaxf(p.cnew4[n].w, 1e-8f);
  if (same){
    int ct = cds[0];
    int4 cv = ((const int4*)p.idxOld)[ct];
    int ov = 0;
    ov += (cv.x == ni.x || cv.x == ni.y || cv.x == ni.z || cv.x == ni.w) ? 1 : 0;
    ov += (cv.y == ni.x || cv.y == ni.y || cv.y == ni.z || cv.y == ni.w) ? 1 : 0;
    ov += (cv.z == ni.x || cv.z == ni.y || cv.z == ni.z || cv.z == ni.w) ? 1 : 0;
    ov += (cv.w == ni.x || cv.w == ni.y || cv.w == ni.z || cv.w == ni.w) ? 1 : 0;
    float d0 = p.occ[ct * 3 + 0] - nc0;
    float d1 = p.occ[ct * 3 + 1] - nc1;
    float d2 = p.occ[ct * 3 + 2] - nc2;
    float ccd2 = (d0 * d0 + d1 * d1) + d2 * d2;
    float raw = expf((float)ov * 2.0f) / (ccd2 + 1e-8f);
    float rsum = 0.0f;
    rsum += raw; rsum += raw; rsum += raw; rsum += raw; rsum += raw;
    float wgt = raw / rsum;
    float ds = p.cold4[ct].w / nelv;
    ds = fminf(fmaxf(ds, 0.1f), 10.0f);
    float cf = (float)ct;
    for (int c = 0; c < 5; ++c){
      p.out[n * 5 + c] = cf;
      p.out[TNEW * 5 + n * 5 + c] = wgt;
      p.out[2 * TNEW * 5 + n * 5 + c] = ds;
    }
    return;
  }
  float raws[5]; float rsum = 0.0f;
  float oels[5];
  for (int c = 0; c < 5; ++c){
    int ct = cds[c];
    int4 cv = ((const int4*)p.idxOld)[ct];
    int ov = 0;
    ov += (cv.x == ni.x || cv.x == ni.y || cv.x == ni.z || cv.x == ni.w) ? 1 : 0;
    ov += (cv.y == ni.x || cv.y == ni.y || cv.y == ni.z || cv.y == ni.w) ? 1 : 0;
    ov += (cv.z == ni.x || cv.z == ni.y || cv.z == ni.z || cv.z == ni.w) ? 1 : 0;
    ov += (cv.w == ni.x || cv.w == ni.y || cv.w == ni.z || cv.w == ni.w) ? 1 : 0;
    float d0 = p.occ[ct * 3 + 0] - nc0;
    float d1 = p.occ[ct * 3 + 1] - nc1;
    float d2 = p.occ[ct * 3 + 2] - nc2;
    float ccd2 = (d0 * d0 + d1 * d1) + d2 * d2;
    float raw = expf((float)ov * 2.0f) / (ccd2 + 1e-8f);
    raws[c] = raw; rsum += raw;
    oels[c] = p.cold4[ct].w;
  }
  for (int c = 0; c < 5; ++c){
    p.out[n * 5 + c] = (float)cds[c];
    p.out[TNEW * 5 + n * 5 + c] = raws[c] / rsum;
    float ds = oels[c] / nelv;
    ds = fminf(fmaxf(ds, 0.1f), 10.0f);
    p.out[2 * TNEW * 5 + n * 5 + c] = ds;
  }
}

// K4: every block derives S from the histogram (exact, wave-uniform reads).
// Blocks [0,120): scan own 500-walker slice for fallback-owned (sstep > S),
// collect hits in LDS, cooperative nearest-centroid + inline assemble.
// Blocks [120,355): assemble all other walkers. Exact disjoint partition.
__global__ __launch_bounds__(256) void k_tail(P p){
  __shared__ float sd[256];
  __shared__ int si[256];
  __shared__ int s_hits[256];
  __shared__ int s_nhits;
  __shared__ int s_S;
  if (threadIdx.x == 0) s_S = compute_S(p.counters);
  __syncthreads();
  int S = s_S;
  int bb = blockIdx.x;
  if (bb < NB_FB){
    int base = bb * FBRANGE;
    for (int chunk = base; chunk < base + FBRANGE; chunk += 256){
      if (threadIdx.x == 0) s_nhits = 0;
      __syncthreads();
      int n = chunk + threadIdx.x;
      if (n < base + FBRANGE && n < TNEW){
        if (p.matched[n] < 0 && p.sstep[n] > S)
          s_hits[atomicAdd(&s_nhits, 1)] = n;
      }
      __syncthreads();
      int nh = s_nhits;
      for (int h = 0; h < nh; ++h){
        int n2 = s_hits[h];
        float4 cn = p.cnew4[n2];
        float cx = cn.x, cy = cn.y, cz = cn.z;
        float p2 = (cx * cx + cy * cy) + cz * cz;
        float bd = 3.402823466e+38f; int bi = 0;
        for (int j = threadIdx.x; j < TOLD; j += 256){
          float4 oc = p.cold4[j];
          float dot = (cx * oc.x + cy * oc.y) + cz * oc.z;
          float c2 = (oc.x * oc.x + oc.y * oc.y) + oc.z * oc.z;
          float d = (p2 - 2.0f * dot) + c2;
          if (d < bd || (d == bd && j < bi)){ bd = d; bi = j; }
        }
        sd[threadIdx.x] = bd; si[threadIdx.x] = bi;
        __syncthreads();
        for (int s = 128; s > 0; s >>= 1){
          if ((int)threadIdx.x < s){
            float od = sd[threadIdx.x + s]; int oi = si[threadIdx.x + s];
            if (od < sd[threadIdx.x] || (od == sd[threadIdx.x] && oi < si[threadIdx.x])){
              sd[threadIdx.x] = od; si[threadIdx.x] = oi;
            }
          }
          __syncthreads();
        }
        if (threadIdx.x == 0){
          int r = si[0];
          if (r < 0) r = 0; if (r > TOLD - 1) r = TOLD - 1;
          assemble_walker(p, n2, -1, r);
        }
        __syncthreads();
      }
      __syncthreads();
    }
  } else {
    int n = (bb - NB_FB) * 256 + threadIdx.x;
    if (n >= TNEW) return;
    int m = p.matched[n];
    int remap = 0;
    if (m < 0){
      if (p.sstep[n] > S) return;                    // fallback blocks own it
      remap = p.rem[n];
    }
    assemble_walker(p, n, m, remap);
  }
}

extern "C" void kernel_launch(void* const* d_in, const int* in_sizes, int n_in,
                              void* d_out, int out_size, void* d_ws, size_t ws_size,
                              hipStream_t stream) {
  char* w = (char*)d_ws;
  P p;
  p.rawNew = (const unsigned int*)d_in[0];
  p.rawOld = (const unsigned int*)d_in[1];
  p.occ    = (const float*)d_in[2];
  p.ncc    = (const float*)d_in[3];
  p.verts  = (const float*)d_in[4];
  p.out    = (float*)d_out;
  p.tkeys    = (unsigned long long*)(w + OFF_TKEYS);
  p.ftab     = (unsigned long long*)(w + OFF_FTAB);
  p.nbr      = (int*)(w + OFF_NBR);
  p.counters = (int*)(w + OFF_CNT);
  p.tvals    = (int*)(w + OFF_TVALS);
  p.pprio    = (int*)(w + OFF_PPRIO);
  p.prio     = (int*)(w + OFF_PRIO);
  p.idxOld   = (int*)(w + OFF_IDXOLD);
  p.sstep    = (int*)(w + OFF_SSTEP);
  p.rem      = (int*)(w + OFF_REM);
  p.degen    = (int*)(w + OFF_DEGEN);
  p.matched  = (int*)(w + OFF_MATCHED);
  p.Tv4      = (float4*)(w + OFF_TV4);
  p.cold4    = (float4*)(w + OFF_COLD4);
  p.cnew4    = (float4*)(w + OFF_CNEW4);
  p.dm       = (unsigned long long*)(w + OFF_DM);
  size_t avail = (ws_size > (size_t)OFF_DM) ? ws_size - (size_t)OFF_DM : 0;
  unsigned dmMask = 0;
  for (int bshift = 21; bshift >= 16; --bshift){
    if (avail >= ((size_t)8 << bshift)){ dmMask = (1u << bshift) - 1u; break; }
  }
  p.dmMask = dmMask;

  hipMemsetAsync(w, 0xFF, FF_BYTES, stream);
  hipLaunchKernelGGL(k_front,   dim3(NB_SETUP + NB_PRIO + NB_NEWG), dim3(256), 0, stream, p);
  hipLaunchKernelGGL(k_mid,     dim3(NB_FACE + NB_FOLD + NB_MATCH), dim3(256), 0, stream, p);
  hipLaunchKernelGGL(k_walkall, dim3((TNEW + 255) / 256), dim3(256), 0, stream, p);
  hipLaunchKernelGGL(k_tail,    dim3(NB_FB + NB_ASM), dim3(256), 0, stream, p);
}

// Round 13
// 113.825 us; speedup vs baseline: 7.0147x; 1.0132x over previous
//
#include <hip/hip_runtime.h>

#pragma clang fp contract(off)

#define TOLD 60000
#define TNEW 60000
#define NVERT 30000
#define MAXSTEPS 300
#define THSZ 131072                  // tet-key hash slots (exact, CAS)
#define FHSZ 131072                  // exact CAS face table (DM-collision fallback only)
#define EMPTY64 0xFFFFFFFFFFFFFFFFULL
#define NWGR 60                      // prio vertex ranges (500 verts each)
#define VRANGE 500
#define NSLICE 16                    // prio tet slices
#define TSLICE (TOLD / NSLICE)       // 3750

// K1 block-range split
#define NB_SETUP 235                 // ceil(60000/256)
#define NB_PRIO  (NWGR * NSLICE)     // 960
#define NB_NEWG  235
// K2 block-range split
#define NB_FACE  938                 // ceil(240000/256)
#define NB_FOLD  118                 // ceil(30000/256)
#define NB_MATCH 235                 // tet-match probe for new tets
// K_tail: repair-only pass
#define NB_FB    120                 // fallback blocks (scan 500 walkers each)
#define FBRANGE  (TNEW / NB_FB)      // 500

// workspace layout: [0xFF-init region][rest, no init needed]
#define OFF_TKEYS    0u              // 131072*8 = 1,048,576
#define OFF_FTAB     1048576u        // 131072*8 = 1,048,576
#define OFF_NBR      2097152u        // 240000*4 =   960,000
#define FF_BYTES     3057152u        // end of 0xFF region
#define OFF_CNT      3057152u        // 2048 B: counters[0..63] + hist[64..365] (zeroed by k_front blk0)
#define OFF_TVALS    3059200u        // 524,288 (poison-safe)
#define OFF_PPRIO    3583488u        // 1,920,000 (fully written by prio2 part)
#define OFF_PRIO     5503488u        // 120,000 (fully written by fold part)
#define OFF_IDXOLD   5623488u        // 960,000 (16B aligned)
#define OFF_SSTEP    6583488u        // 240,000 (settle step per walker; only read when matched<0)
#define OFF_DEGEN    6823488u        // 240,000
#define OFF_MATCHED  7063488u        // 240,000
#define OFF_TV4      7303488u        // 2,880,000 (3 float4/tet: Tinv row + v0 comp)
#define OFF_COLD4    10183488u       // 960,000 (centroid, oel)
#define OFF_CNEW4    11143488u       // 960,000 (centroid, nel)
#define OFF_DM       12103488u       // 64-bit keyed DM face table (uninit/poison-safe)

struct P {
  const unsigned int* rawNew;
  const unsigned int* rawOld;
  const float* occ;
  const float* ncc;
  const float* verts;
  float* out;
  unsigned long long* tkeys;
  unsigned long long* ftab;
  int* counters;   // [0]=n_walk; [64..365]=hist[s] (settle-step histogram)
  int* tvals;
  int* idxOld;
  int* nbr;
  int* pprio;
  int* prio;
  int* sstep;
  int* degen;
  int* matched;
  float4* Tv4;
  float4* cold4;
  float4* cnew4;
  unsigned long long* dm;            // (key<<18 | tet*4+local), racy last-wins
  unsigned int dmMask;
};

__device__ __forceinline__ unsigned hash64(unsigned long long k){
  k ^= k >> 33; k *= 0xff51afd7ed558ccdULL;
  k ^= k >> 33; k *= 0xc4ceb9fe1a85ec53ULL;
  k ^= k >> 33;
  return (unsigned)k;
}
__device__ __forceinline__ void cswap(int& a, int& b){ if (a > b){ int t = a; a = b; b = t; } }

__device__ __forceinline__ int detect64(const unsigned int* raw){
  unsigned acc = 0;
  const uint4* r4 = (const uint4*)raw;
  #pragma unroll
  for (int k = 0; k < 32; ++k){ uint4 v = r4[k]; acc |= (v.y | v.w); }
  return acc == 0u;
}

__device__ __forceinline__ int4 load_tet4(const unsigned int* raw, int is64, int t){
  if (is64){
    uint4 a = ((const uint4*)raw)[t * 2 + 0];
    uint4 b = ((const uint4*)raw)[t * 2 + 1];
    return make_int4((int)a.x, (int)a.z, (int)b.x, (int)b.z);
  }
  uint4 a = ((const uint4*)raw)[t];
  return make_int4((int)a.x, (int)a.y, (int)a.z, (int)a.w);
}

__device__ __forceinline__ void face_insert(unsigned long long* ftab, int* nbr,
                                            unsigned long long fkey, int t, int l){
  unsigned long long mine = (fkey << 18) | (unsigned long long)(t * 4 + l);
  unsigned slot = hash64(fkey ^ 0x9e3779b97f4a7c15ULL) & (FHSZ - 1);
  while (true){
    unsigned long long prev = atomicCAS(&ftab[slot], EMPTY64, mine);
    if (prev == EMPTY64) return;
    if ((prev >> 18) == fkey){
      int oid = (int)(prev & 0x3FFFFULL);
      nbr[t * 4 + l] = oid >> 2;
      nbr[oid] = t;
      return;
    }
    slot = (slot + 1) & (FHSZ - 1);
  }
}

__device__ __forceinline__ float min_edge_r(
    float q0x, float q0y, float q0z, float q1x, float q1y, float q1z,
    float q2x, float q2y, float q2z, float q3x, float q3y, float q3z){
  float m = 3.402823466e+38f;
  float dx, dy, dz, d;
  dx = q0x - q1x; dy = q0y - q1y; dz = q0z - q1z; d = sqrtf((dx*dx + dy*dy) + dz*dz); m = fminf(m, d);
  dx = q0x - q2x; dy = q0y - q2y; dz = q0z - q2z; d = sqrtf((dx*dx + dy*dy) + dz*dz); m = fminf(m, d);
  dx = q0x - q3x; dy = q0y - q3y; dz = q0z - q3z; d = sqrtf((dx*dx + dy*dy) + dz*dz); m = fminf(m, d);
  dx = q1x - q2x; dy = q1y - q2y; dz = q1z - q2z; d = sqrtf((dx*dx + dy*dy) + dz*dz); m = fminf(m, d);
  dx = q1x - q3x; dy = q1y - q3y; dz = q1z - q3z; d = sqrtf((dx*dx + dy*dy) + dz*dz); m = fminf(m, d);
  dx = q2x - q3x; dy = q2y - q3y; dz = q2z - q3z; d = sqrtf((dx*dx + dy*dy) + dz*dz); m = fminf(m, d);
  return m;
}

// K1: setup [0,235) | prio partial-max [235,1195) | new-geometry [1195,1430)
__global__ __launch_bounds__(256) void k_front(P p){
  __shared__ int sprio[VRANGE];
  int bb = blockIdx.x;
  if (bb < NB_SETUP){
    int t = bb * 256 + threadIdx.x;
    if (bb == 0){
      for (int j = threadIdx.x; j < 384; j += 256) p.counters[j] = 0;
    }
    if (t >= TOLD) return;
    int is64 = detect64(p.rawOld);
    int4 iv4 = load_tet4(p.rawOld, is64, t);
    int i0 = iv4.x, i1 = iv4.y, i2 = iv4.z, i3 = iv4.w;
    ((int4*)p.idxOld)[t] = iv4;

    // tet key insert; CAS winner plain-stores value, dup-key path (P~5e-8)
    // uses atomicMax. tvals poison (negative) always loses the max.
    {
      int s0 = i0, s1 = i1, s2 = i2, s3 = i3;
      cswap(s0, s1); cswap(s2, s3); cswap(s0, s2); cswap(s1, s3); cswap(s1, s2);
      unsigned long long key =
          (unsigned long long)((((long long)s0 * NVERT + s1) * NVERT + s2) * NVERT + s3);
      unsigned slot = hash64(key) & (THSZ - 1);
      while (true){
        unsigned long long prev = atomicCAS(&p.tkeys[slot], EMPTY64, key);
        if (prev == EMPTY64){ p.tvals[slot] = t; break; }
        if (prev == key){ atomicMax(&p.tvals[slot], t); break; }
        slot = (slot + 1) & (THSZ - 1);
      }
    }

    // 64-bit keyed DM face writes (racy last-wins; resolved in k_mid)
    if (p.dmMask){
      const int FO[4][3] = {{1, 2, 3}, {0, 2, 3}, {0, 1, 3}, {0, 1, 2}};
      int iv[4] = {i0, i1, i2, i3};
      #pragma unroll
      for (int l = 0; l < 4; ++l){
        int a = iv[FO[l][0]], b = iv[FO[l][1]], c = iv[FO[l][2]];
        cswap(a, b); cswap(a, c); cswap(b, c);
        unsigned long long fk = (unsigned long long)(((long long)a * NVERT + b) * NVERT + c);
        p.dm[hash64(fk) & p.dmMask] = (fk << 18) | (unsigned long long)(t * 4 + l);
      }
    }

    float q0x = p.verts[i0 * 3 + 0], q0y = p.verts[i0 * 3 + 1], q0z = p.verts[i0 * 3 + 2];
    float q1x = p.verts[i1 * 3 + 0], q1y = p.verts[i1 * 3 + 1], q1z = p.verts[i1 * 3 + 2];
    float q2x = p.verts[i2 * 3 + 0], q2y = p.verts[i2 * 3 + 1], q2z = p.verts[i2 * 3 + 2];
    float q3x = p.verts[i3 * 3 + 0], q3y = p.verts[i3 * 3 + 1], q3z = p.verts[i3 * 3 + 2];
    float e1x = q1x - q0x, e1y = q1y - q0y, e1z = q1z - q0z;
    float e2x = q2x - q0x, e2y = q2y - q0y, e2z = q2z - q0z;
    float e3x = q3x - q0x, e3y = q3y - q0y, e3z = q3z - q0z;
    float c23x = e2y * e3z - e2z * e3y;
    float c23y = e2z * e3x - e2x * e3z;
    float c23z = e2x * e3y - e2y * e3x;
    float det = e1x * c23x + e1y * c23y + e1z * c23z;
    int dg = (fabsf(det) < 1e-10f) ? 1 : 0;
    p.degen[t] = dg;
    float4 r0, r1, r2;
    if (dg){
      r0 = make_float4(1.f, 0.f, 0.f, q0x);
      r1 = make_float4(0.f, 1.f, 0.f, q0y);
      r2 = make_float4(0.f, 0.f, 1.f, q0z);
    } else {
      float inv = 1.0f / det;
      float c31x = e3y * e1z - e3z * e1y;
      float c31y = e3z * e1x - e3x * e1z;
      float c31z = e3x * e1y - e3y * e1x;
      float c12x = e1y * e2z - e1z * e2y;
      float c12y = e1z * e2x - e1x * e2z;
      float c12z = e1x * e2y - e1y * e2x;
      r0 = make_float4(c23x * inv, c23y * inv, c23z * inv, q0x);
      r1 = make_float4(c31x * inv, c31y * inv, c31z * inv, q0y);
      r2 = make_float4(c12x * inv, c12y * inv, c12z * inv, q0z);
    }
    p.Tv4[t * 3 + 0] = r0;
    p.Tv4[t * 3 + 1] = r1;
    p.Tv4[t * 3 + 2] = r2;
    float el = min_edge_r(q0x, q0y, q0z, q1x, q1y, q1z, q2x, q2y, q2z, q3x, q3y, q3z);
    p.cold4[t] = make_float4((((q0x + q1x) + q2x) + q3x) * 0.25f,
                             (((q0y + q1y) + q2y) + q3y) * 0.25f,
                             (((q0z + q1z) + q2z) + q3z) * 0.25f, el);
  } else if (bb < NB_SETUP + NB_PRIO){
    int rb = bb - NB_SETUP;
    int range = rb / NSLICE;
    int slice = rb % NSLICE;
    int base = range * VRANGE;
    for (int j = threadIdx.x; j < VRANGE; j += 256) sprio[j] = -1;
    __syncthreads();
    int is64 = detect64(p.rawOld);
    int t0 = slice * TSLICE;
    for (int t = t0 + threadIdx.x; t < t0 + TSLICE; t += 256){
      int4 iv = load_tet4(p.rawOld, is64, t);
      int v;
      v = iv.x - base; if ((unsigned)v < VRANGE) atomicMax(&sprio[v], 0 * TOLD + t);
      v = iv.y - base; if ((unsigned)v < VRANGE) atomicMax(&sprio[v], 1 * TOLD + t);
      v = iv.z - base; if ((unsigned)v < VRANGE) atomicMax(&sprio[v], 2 * TOLD + t);
      v = iv.w - base; if ((unsigned)v < VRANGE) atomicMax(&sprio[v], 3 * TOLD + t);
    }
    __syncthreads();
    for (int j = threadIdx.x; j < VRANGE; j += 256)
      p.pprio[slice * NVERT + base + j] = sprio[j];
  } else {
    int n = (bb - NB_SETUP - NB_PRIO) * 256 + threadIdx.x;
    if (n >= TNEW) return;
    int is64 = detect64(p.rawNew);
    int4 ni = load_tet4(p.rawNew, is64, n);
    float q0x = p.verts[ni.x * 3 + 0], q0y = p.verts[ni.x * 3 + 1], q0z = p.verts[ni.x * 3 + 2];
    float q1x = p.verts[ni.y * 3 + 0], q1y = p.verts[ni.y * 3 + 1], q1z = p.verts[ni.y * 3 + 2];
    float q2x = p.verts[ni.z * 3 + 0], q2y = p.verts[ni.z * 3 + 1], q2z = p.verts[ni.z * 3 + 2];
    float q3x = p.verts[ni.w * 3 + 0], q3y = p.verts[ni.w * 3 + 1], q3z = p.verts[ni.w * 3 + 2];
    float el = min_edge_r(q0x, q0y, q0z, q1x, q1y, q1z, q2x, q2y, q2z, q3x, q3y, q3z);
    p.cnew4[n] = make_float4((((q0x + q1x) + q2x) + q3x) * 0.25f,
                             (((q0y + q1y) + q2y) + q3y) * 0.25f,
                             (((q0z + q1z) + q2z) + q3z) * 0.25f, el);
  }
}

// K2: face resolve [0,938) + pprio fold [938,1056) + new-tet match probe [1056,1291)
__global__ __launch_bounds__(256) void k_mid(P p){
  int bb = blockIdx.x;
  if (bb < NB_FACE){
    int i = bb * 256 + threadIdx.x;
    if (i >= TOLD * 4) return;
    int t = i >> 2, l = i & 3;
    int4 iv4 = ((const int4*)p.idxOld)[t];
    int iv[4] = {iv4.x, iv4.y, iv4.z, iv4.w};
    const int FO[4][3] = {{1, 2, 3}, {0, 2, 3}, {0, 1, 3}, {0, 1, 2}};
    int a = iv[FO[l][0]], b = iv[FO[l][1]], c = iv[FO[l][2]];
    cswap(a, b); cswap(a, c); cswap(b, c);
    unsigned long long fk = (unsigned long long)(((long long)a * NVERT + b) * NVERT + c);
    if (p.dmMask){
      unsigned long long mine = (fk << 18) | (unsigned long long)i;
      unsigned long long got = p.dm[hash64(fk) & p.dmMask];
      if (got == mine) return;                       // self-winner; partner links both
      if ((got >> 18) == fk){                        // key-verified partner
        int wid = (int)(got & 0x3FFFFULL);
        p.nbr[i] = wid >> 2;
        p.nbr[wid] = t;
        return;
      }
    }
    face_insert(p.ftab, p.nbr, fk, t, l);            // bucket collision: exact CAS
  } else if (bb < NB_FACE + NB_FOLD){
    int v = (bb - NB_FACE) * 256 + threadIdx.x;
    if (v >= NVERT) return;
    int pr = -1;
    #pragma unroll
    for (int s = 0; s < NSLICE; ++s) pr = max(pr, p.pprio[s * NVERT + v]);
    p.prio[v] = pr;
  } else {
    int n = (bb - NB_FACE - NB_FOLD) * 256 + threadIdx.x;
    if (n >= TNEW) return;
    int is64 = detect64(p.rawNew);
    int4 ni = load_tet4(p.rawNew, is64, n);
    int s0 = ni.x, s1 = ni.y, s2 = ni.z, s3 = ni.w;
    cswap(s0, s1); cswap(s2, s3); cswap(s0, s2); cswap(s1, s3); cswap(s1, s2);
    unsigned long long key =
        (unsigned long long)((((long long)s0 * NVERT + s1) * NVERT + s2) * NVERT + s3);
    int m = -1;
    unsigned slot = hash64(key) & (THSZ - 1);
    while (true){
      unsigned long long k = p.tkeys[slot];
      if (k == EMPTY64) break;
      if (k == key){ m = p.tvals[slot]; break; }
      slot = (slot + 1) & (THSZ - 1);
    }
    p.matched[n] = m;
  }
}

// Per-walker output assembly. Fast path when all 5 candidates coincide.
__device__ __forceinline__ void assemble_walker(const P& p, int n, int m, int remap){
  int cds[5];
  if (m >= 0){
    cds[0] = cds[1] = cds[2] = cds[3] = cds[4] = m;
  } else {
    cds[0] = remap;
    int dg = p.degen[remap];
    int4 nb4 = ((const int4*)p.nbr)[remap];
    int nbl[4] = {nb4.x, nb4.y, nb4.z, nb4.w};
    for (int l = 0; l < 4; ++l){
      int fb = dg ? -1 : nbl[l];
      cds[1 + l] = (fb >= 0) ? fb : remap;
    }
  }
  bool same = (cds[1] == cds[0]) & (cds[2] == cds[0]) &
              (cds[3] == cds[0]) & (cds[4] == cds[0]);
  int is64 = detect64(p.rawNew);
  int4 ni = load_tet4(p.rawNew, is64, n);
  float nc0 = p.ncc[n * 3 + 0], nc1 = p.ncc[n * 3 + 1], nc2 = p.ncc[n * 3 + 2];
  float nelv = fmaxf(p.cnew4[n].w, 1e-8f);
  if (same){
    int ct = cds[0];
    int4 cv = ((const int4*)p.idxOld)[ct];
    int ov = 0;
    ov += (cv.x == ni.x || cv.x == ni.y || cv.x == ni.z || cv.x == ni.w) ? 1 : 0;
    ov += (cv.y == ni.x || cv.y == ni.y || cv.y == ni.z || cv.y == ni.w) ? 1 : 0;
    ov += (cv.z == ni.x || cv.z == ni.y || cv.z == ni.z || cv.z == ni.w) ? 1 : 0;
    ov += (cv.w == ni.x || cv.w == ni.y || cv.w == ni.z || cv.w == ni.w) ? 1 : 0;
    float d0 = p.occ[ct * 3 + 0] - nc0;
    float d1 = p.occ[ct * 3 + 1] - nc1;
    float d2 = p.occ[ct * 3 + 2] - nc2;
    float ccd2 = (d0 * d0 + d1 * d1) + d2 * d2;
    float raw = expf((float)ov * 2.0f) / (ccd2 + 1e-8f);
    float rsum = 0.0f;
    rsum += raw; rsum += raw; rsum += raw; rsum += raw; rsum += raw;
    float wgt = raw / rsum;
    float ds = p.cold4[ct].w / nelv;
    ds = fminf(fmaxf(ds, 0.1f), 10.0f);
    float cf = (float)ct;
    for (int c = 0; c < 5; ++c){
      p.out[n * 5 + c] = cf;
      p.out[TNEW * 5 + n * 5 + c] = wgt;
      p.out[2 * TNEW * 5 + n * 5 + c] = ds;
    }
    return;
  }
  float raws[5]; float rsum = 0.0f;
  float oels[5];
  for (int c = 0; c < 5; ++c){
    int ct = cds[c];
    int4 cv = ((const int4*)p.idxOld)[ct];
    int ov = 0;
    ov += (cv.x == ni.x || cv.x == ni.y || cv.x == ni.z || cv.x == ni.w) ? 1 : 0;
    ov += (cv.y == ni.x || cv.y == ni.y || cv.y == ni.z || cv.y == ni.w) ? 1 : 0;
    ov += (cv.z == ni.x || cv.z == ni.y || cv.z == ni.z || cv.z == ni.w) ? 1 : 0;
    ov += (cv.w == ni.x || cv.w == ni.y || cv.w == ni.z || cv.w == ni.w) ? 1 : 0;
    float d0 = p.occ[ct * 3 + 0] - nc0;
    float d1 = p.occ[ct * 3 + 1] - nc1;
    float d2 = p.occ[ct * 3 + 2] - nc2;
    float ccd2 = (d0 * d0 + d1 * d1) + d2 * d2;
    float raw = expf((float)ov * 2.0f) / (ccd2 + 1e-8f);
    raws[c] = raw; rsum += raw;
    oels[c] = p.cold4[ct].w;
  }
  for (int c = 0; c < 5; ++c){
    p.out[n * 5 + c] = (float)cds[c];
    p.out[TNEW * 5 + n * 5 + c] = raws[c] / rsum;
    float ds = oels[c] / nelv;
    ds = fminf(fmaxf(ds, 0.1f), 10.0f);
    p.out[2 * TNEW * 5 + n * 5 + c] = ds;
  }
}

// K3: per-walker local walk + LDS histogram + SPECULATIVE full assembly.
// A walker's output depends on the global stop-step S only via the partition
// settled(s<=S) vs fallback(s>S); we assemble as-if settled here (matched
// walkers have no S dependence at all), and K4 repairs the (normally empty)
// fallback set by overwriting those rows. Kernel-boundary ordering makes the
// overwrite race-free.
__global__ __launch_bounds__(256) void k_walkall(P p){
  __shared__ int s_hist[MAXSTEPS + 2];               // bins 0..301
  __shared__ int s_nw;
  for (int j = threadIdx.x; j < MAXSTEPS + 2; j += 256) s_hist[j] = 0;
  if (threadIdx.x == 0) s_nw = 0;
  __syncthreads();
  int n = blockIdx.x * blockDim.x + threadIdx.x;
  if (n < TNEW){
    int m = p.matched[n];
    if (m >= 0){
      assemble_walker(p, n, m, 0);                   // exact; S-independent
    } else {
      atomicAdd(&s_nw, 1);                           // LDS
      int is64 = detect64(p.rawNew);
      int i0 = is64 ? (int)((const long long*)p.rawNew)[n * 4] : ((const int*)p.rawNew)[n * 4];
      int pr = p.prio[i0];
      int c = (pr >= 0) ? (pr % TOLD) : 0;           // seed
      float4 cn = p.cnew4[n];
      int s = MAXSTEPS + 1;                          // 301 = never settles
      for (int k = 1; k <= MAXSTEPS; ++k){
        float4 r0 = p.Tv4[c * 3 + 0];
        float4 r1 = p.Tv4[c * 3 + 1];
        float4 r2 = p.Tv4[c * 3 + 2];
        float rx = cn.x - r0.w, ry = cn.y - r1.w, rz = cn.z - r2.w;
        float b0 = r0.x * rx + r0.y * ry + r0.z * rz;
        float b1 = r1.x * rx + r1.y * ry + r1.z * rz;
        float b2 = r2.x * rx + r2.y * ry + r2.z * rz;
        float a0 = 1.0f - (b0 + b1 + b2);
        float ab[4] = {a0, b0, b1, b2};
        int amin = 0; float mn = ab[0];
        for (int j = 1; j < 4; ++j){ if (ab[j] < mn){ mn = ab[j]; amin = j; } }
        if (mn >= -0.0001f){ s = k; break; }                    // converged
        int nb = p.degen[c] ? -1 : p.nbr[c * 4 + amin];
        if (nb < 0){ s = k; break; }                            // boundary
        c = nb;
      }
      p.sstep[n] = s;
      atomicAdd(&s_hist[s], 1);                      // LDS
      assemble_walker(p, n, -1, c);                  // speculative (settled c)
    }
  }
  __syncthreads();
  if (threadIdx.x == 0 && s_nw) atomicAdd(&p.counters[0], s_nw);
  for (int j = threadIdx.x; j < MAXSTEPS + 2; j += 256){
    int v = s_hist[j];
    if (v) atomicAdd(&p.counters[64 + j], v);        // ~1-2 nonzero bins/block
  }
}

// Exact loop-exit step from the settle-step histogram:
// count_k = nw - sum_{j<=k} hist[j]; S = first k in [0,300] with count_k < thr
// (thr = max(100, nw/1000)), else 300 (MAXSTEPS bound).
__device__ __forceinline__ int compute_S(const int* counters){
  int nw = counters[0];
  int thr = max(100, nw / 1000);
  if (nw < thr) return 0;
  int cnt = nw;
  for (int k = 1; k <= MAXSTEPS; ++k){
    cnt -= counters[64 + k];
    if (cnt < thr) return k;
  }
  return MAXSTEPS;
}

// K4: repair pass only. Each block derives S, scans its 500-walker slice for
// fallback-owned walkers (matched<0 && sstep>S; normally zero), and for hits
// runs the cooperative nearest-centroid fallback + re-assembly, overwriting
// the speculative rows from K3.
__global__ __launch_bounds__(256) void k_tail(P p){
  __shared__ float sd[256];
  __shared__ int si[256];
  __shared__ int s_hits[256];
  __shared__ int s_nhits;
  __shared__ int s_S;
  if (threadIdx.x == 0) s_S = compute_S(p.counters);
  __syncthreads();
  int S = s_S;
  int base = blockIdx.x * FBRANGE;
  for (int chunk = base; chunk < base + FBRANGE; chunk += 256){
    if (threadIdx.x == 0) s_nhits = 0;
    __syncthreads();
    int n = chunk + threadIdx.x;
    if (n < base + FBRANGE && n < TNEW){
      if (p.matched[n] < 0 && p.sstep[n] > S)
        s_hits[atomicAdd(&s_nhits, 1)] = n;
    }
    __syncthreads();
    int nh = s_nhits;
    for (int h = 0; h < nh; ++h){
      int n2 = s_hits[h];
      float4 cn = p.cnew4[n2];
      float cx = cn.x, cy = cn.y, cz = cn.z;
      float p2 = (cx * cx + cy * cy) + cz * cz;
      float bd = 3.402823466e+38f; int bi = 0;
      for (int j = threadIdx.x; j < TOLD; j += 256){
        float4 oc = p.cold4[j];
        float dot = (cx * oc.x + cy * oc.y) + cz * oc.z;
        float c2 = (oc.x * oc.x + oc.y * oc.y) + oc.z * oc.z;
        float d = (p2 - 2.0f * dot) + c2;
        if (d < bd || (d == bd && j < bi)){ bd = d; bi = j; }
      }
      sd[threadIdx.x] = bd; si[threadIdx.x] = bi;
      __syncthreads();
      for (int s = 128; s > 0; s >>= 1){
        if ((int)threadIdx.x < s){
          float od = sd[threadIdx.x + s]; int oi = si[threadIdx.x + s];
          if (od < sd[threadIdx.x] || (od == sd[threadIdx.x] && oi < si[threadIdx.x])){
            sd[threadIdx.x] = od; si[threadIdx.x] = oi;
          }
        }
        __syncthreads();
      }
      if (threadIdx.x == 0){
        int r = si[0];
        if (r < 0) r = 0; if (r > TOLD - 1) r = TOLD - 1;
        assemble_walker(p, n2, -1, r);
      }
      __syncthreads();
    }
    __syncthreads();
  }
}

extern "C" void kernel_launch(void* const* d_in, const int* in_sizes, int n_in,
                              void* d_out, int out_size, void* d_ws, size_t ws_size,
                              hipStream_t stream) {
  char* w = (char*)d_ws;
  P p;
  p.rawNew = (const unsigned int*)d_in[0];
  p.rawOld = (const unsigned int*)d_in[1];
  p.occ    = (const float*)d_in[2];
  p.ncc    = (const float*)d_in[3];
  p.verts  = (const float*)d_in[4];
  p.out    = (float*)d_out;
  p.tkeys    = (unsigned long long*)(w + OFF_TKEYS);
  p.ftab     = (unsigned long long*)(w + OFF_FTAB);
  p.nbr      = (int*)(w + OFF_NBR);
  p.counters = (int*)(w + OFF_CNT);
  p.tvals    = (int*)(w + OFF_TVALS);
  p.pprio    = (int*)(w + OFF_PPRIO);
  p.prio     = (int*)(w + OFF_PRIO);
  p.idxOld   = (int*)(w + OFF_IDXOLD);
  p.sstep    = (int*)(w + OFF_SSTEP);
  p.degen    = (int*)(w + OFF_DEGEN);
  p.matched  = (int*)(w + OFF_MATCHED);
  p.Tv4      = (float4*)(w + OFF_TV4);
  p.cold4    = (float4*)(w + OFF_COLD4);
  p.cnew4    = (float4*)(w + OFF_CNEW4);
  p.dm       = (unsigned long long*)(w + OFF_DM);
  size_t avail = (ws_size > (size_t)OFF_DM) ? ws_size - (size_t)OFF_DM : 0;
  unsigned dmMask = 0;
  for (int bshift = 21; bshift >= 16; --bshift){
    if (avail >= ((size_t)8 << bshift)){ dmMask = (1u << bshift) - 1u; break; }
  }
  p.dmMask = dmMask;

  hipMemsetAsync(w, 0xFF, FF_BYTES, stream);
  hipLaunchKernelGGL(k_front,   dim3(NB_SETUP + NB_PRIO + NB_NEWG), dim3(256), 0, stream, p);
  hipLaunchKernelGGL(k_mid,     dim3(NB_FACE + NB_FOLD + NB_MATCH), dim3(256), 0, stream, p);
  hipLaunchKernelGGL(k_walkall, dim3((TNEW + 255) / 256), dim3(256), 0, stream, p);
  hipLaunchKernelGGL(k_tail,    dim3(NB_FB), dim3(256), 0, stream, p);
}